// Round 17
// baseline (130.045 us; speedup 1.0000x reference)
//
#include <hip/hip_runtime.h>

// SelfAttention: y = causal_mha(x @ W_qkv^T + b_qkv)
// B=4, T=2048, C=1024, H=16, hd=64.  All I/O fp32; compute in bf16 MFMA.
//
// Pipeline:
//   1) cvt2: merged x->xb, W->Wb bf16 convert (one launch)
//   2) qkv_gemm v8 (unchanged): T3 minimum-2-phase prefetch dbuf (64KB LDS),
//      BK=64, specialized epilogue, frag-tiled outputs:
//        qS/kS: (t,d) -> ((t>>5)*4 + (d>>4))*512 + (t&31)*16 + (d&15)
//        vS:    (t,d) -> ((t>>4)*64 + d)*16 + (t&15)
//      Q pre-scaled by 0.125*log2e -> S in log2 domain.
//      (2-phase ceiling ~900TF; at 819TF = 91%.  8-phase 256² rejected:
//       384 blocks / 256 CU = 1.5 dispatch rounds -> 75% tail eats the gain.)
//   3) attn v9d: v9c + V software-pipeline (round-16 diagnosis: V issued at
//      step top, consumed ~400cy later — marginal vs L2/L3 latency with the
//      8bh-per-XCD working set exactly filling 4MB L2).  vf reloaded with
//      V(jt+2) after its last PV use (dead-reg reload, K-pattern mirror,
//      zero extra registers); prologue loads V(p).  Issue->consume ~1.7 steps.

typedef unsigned short u16;
typedef short bf16x8 __attribute__((ext_vector_type(8)));
typedef float f32x4 __attribute__((ext_vector_type(4)));
typedef float f32x16 __attribute__((ext_vector_type(16)));

__device__ __forceinline__ float exp2f_hw(float x) {
  return __builtin_amdgcn_exp2f(x);   // v_exp_f32: 2^x
}

__device__ __forceinline__ u16 f2b(float f) {
  union { float f; unsigned u; } x; x.f = f;
  unsigned r = x.u + 0x7FFFu + ((x.u >> 16) & 1u);  // RNE
  return (u16)(r >> 16);
}

__device__ __forceinline__ unsigned cvtpk(float lo, float hi_) {
  unsigned r;
  asm("v_cvt_pk_bf16_f32 %0, %1, %2" : "=v"(r) : "v"(lo), "v"(hi_));
  return r;
}

__device__ __forceinline__ void gload16(const void* g, void* l) {
  __builtin_amdgcn_global_load_lds(
      (const __attribute__((address_space(1))) unsigned*)g,
      (__attribute__((address_space(3))) unsigned*)l, 16, 0, 0);
}

// P = exp2(st) packed into two PV A-frags (8 cvt_pk + 4 permlane)
__device__ __forceinline__ void packP(f32x16 st, bf16x8& pa0, bf16x8& pa1) {
#pragma unroll
  for (int r = 0; r < 16; ++r) st[r] = exp2f_hw(st[r]);
  {
    unsigned x0 = cvtpk(st[0], st[1]),  y0 = cvtpk(st[4], st[5]);
    unsigned x1 = cvtpk(st[2], st[3]),  y1 = cvtpk(st[6], st[7]);
    auto s0 = __builtin_amdgcn_permlane32_swap(x0, y0, false, false);
    auto s1 = __builtin_amdgcn_permlane32_swap(x1, y1, false, false);
    union { unsigned w[4]; bf16x8 v; } u;
    u.w[0] = s0[0]; u.w[1] = s1[0]; u.w[2] = s0[1]; u.w[3] = s1[1];
    pa0 = u.v;
  }
  {
    unsigned x0 = cvtpk(st[8], st[9]),   y0 = cvtpk(st[12], st[13]);
    unsigned x1 = cvtpk(st[10], st[11]), y1 = cvtpk(st[14], st[15]);
    auto s0 = __builtin_amdgcn_permlane32_swap(x0, y0, false, false);
    auto s1 = __builtin_amdgcn_permlane32_swap(x1, y1, false, false);
    union { unsigned w[4]; bf16x8 v; } u;
    u.w[0] = s0[0]; u.w[1] = s1[0]; u.w[2] = s0[1]; u.w[3] = s1[1];
    pa1 = u.v;
  }
}

// ---------------- merged fp32 -> bf16 convert (x then W) ----------------
__global__ void cvt2(const float* __restrict__ x, u16* __restrict__ xb,
                     const float* __restrict__ W, u16* __restrict__ Wb) {
  const int b = blockIdx.x;
  if (b < 2048) {
    int i = b * 256 + threadIdx.x;
    for (; i < 2097152; i += 2048 * 256) {
      float4 v = ((const float4*)x)[i];
      ushort4 o;
      o.x = f2b(v.x); o.y = f2b(v.y); o.z = f2b(v.z); o.w = f2b(v.w);
      ((ushort4*)xb)[i] = o;
    }
  } else {
    int i = (b - 2048) * 256 + threadIdx.x;
    for (; i < 786432; i += 1024 * 256) {
      float4 v = ((const float4*)W)[i];
      ushort4 o;
      o.x = f2b(v.x); o.y = f2b(v.y); o.z = f2b(v.z); o.w = f2b(v.w);
      ((ushort4*)Wb)[i] = o;
    }
  }
}

// ---------------- QKV GEMM (2-phase prefetch dbuf, specialized epilogue) ----------------
__global__ __launch_bounds__(256) void qkv_gemm(
    const u16* __restrict__ Xb, const u16* __restrict__ Wb,
    const float* __restrict__ bias,
    u16* __restrict__ qw, u16* __restrict__ kw, u16* __restrict__ vw) {
  // [dbuf][As 8192 u16 | Bs 8192 u16]  (64 KB total)
  __shared__ u16 LDSbuf[2][16384];
  const int tid  = threadIdx.x;
  const int lane = tid & 63;
  const int wave = tid >> 6;
  const int ln = lane & 15, hi = lane >> 4;
  const int wr = wave >> 1, wc = wave & 1;
  const int m0 = blockIdx.y * 128;
  const int n0 = blockIdx.x * 128;
  const bool vblk = (n0 >= 2048);

  const int srow = tid >> 2;
  const int scol = (tid & 3) * 8;

  f32x4 zero = {0.f, 0.f, 0.f, 0.f};
  f32x4 acc[4][4];
#pragma unroll
  for (int i = 0; i < 4; ++i)
#pragma unroll
    for (int j = 0; j < 4; ++j) acc[i][j] = zero;

  const u16* Xb0 = Xb + (size_t)(m0 + srow) * 1024 + scol;
  const u16* Xb1 = Xb + (size_t)(m0 + 64 + srow) * 1024 + scol;
  const u16* Wb0 = Wb + (size_t)(n0 + srow) * 1024 + scol;
  const u16* Wb1 = Wb + (size_t)(n0 + 64 + srow) * 1024 + scol;

  // stage K-tile k0 into buffer cur (8 x global_load_lds width=16)
  auto STAGE = [&](int cur, int k0) {
    char* As = (char*)&LDSbuf[cur][0];
    char* Bs = (char*)&LDSbuf[cur][8192];
    gload16(Xb0 + k0,      As + tid * 16);
    gload16(Xb1 + k0,      As + 4096 + tid * 16);
    gload16(Xb0 + k0 + 32, As + 8192 + tid * 16);
    gload16(Xb1 + k0 + 32, As + 12288 + tid * 16);
    gload16(Wb0 + k0,      Bs + tid * 16);
    gload16(Wb1 + k0,      Bs + 4096 + tid * 16);
    gload16(Wb0 + k0 + 32, Bs + 8192 + tid * 16);
    gload16(Wb1 + k0 + 32, Bs + 12288 + tid * 16);
  };

  auto COMPUTE = [&](int cur) {
    const u16* As = &LDSbuf[cur][0];
    const u16* Bs = &LDSbuf[cur][8192];
#pragma unroll
    for (int hf = 0; hf < 2; ++hf) {
      const u16* Ah = As + hf * 4096;
      const u16* Bh = Bs + hf * 4096;
      bf16x8 af[4], bfv[4];
#pragma unroll
      for (int i = 0; i < 4; ++i)
        af[i] = *(const bf16x8*)&Ah[(wr * 64 + i * 16 + ln) * 32 + hi * 8];
#pragma unroll
      for (int j = 0; j < 4; ++j)
        bfv[j] = *(const bf16x8*)&Bh[(wc * 64 + j * 16 + ln) * 32 + hi * 8];
      if (vblk) {
        // C^T: D[row = W-row (d)][col = X-row (t)]
#pragma unroll
        for (int i = 0; i < 4; ++i)
#pragma unroll
          for (int j = 0; j < 4; ++j)
            acc[i][j] = __builtin_amdgcn_mfma_f32_16x16x32_bf16(bfv[j], af[i], acc[i][j], 0, 0, 0);
      } else {
#pragma unroll
        for (int i = 0; i < 4; ++i)
#pragma unroll
          for (int j = 0; j < 4; ++j)
            acc[i][j] = __builtin_amdgcn_mfma_f32_16x16x32_bf16(af[i], bfv[j], acc[i][j], 0, 0, 0);
      }
    }
  };

  // T3 minimum 2-phase: prologue stage, then {STAGE(t+1); COMPUTE(t); barrier}
  STAGE(0, 0);
  __syncthreads();            // tile 0 ready
  int cur = 0;
#pragma unroll 1
  for (int t = 0; t < 15; ++t) {
    STAGE(cur ^ 1, (t + 1) * 64);   // issue next-tile loads FIRST (fly under compute)
    COMPUTE(cur);
    __syncthreads();          // vmcnt(0)+lgkmcnt(0)+barrier: next tile ready,
    cur ^= 1;                 // this tile's reads done -> buf reusable
  }
  COMPUTE(cur);               // last tile, no prefetch

  // ---- epilogue: which/bh uniform per block(+wave) ----
  const int which = n0 >> 10;              // 0=q 1=k 2=v (uniform)
  const int h = ((n0 & 1023) >> 6) + wc;   // head (uniform per wave)
  const size_t bh = (size_t)((m0 >> 11) * 16 + h);
  const int tloc = (m0 & 2047) + wr * 64;  // wave's local t base (mult of 64)

  if (which == 2) {
    u16* ob = vw + bh * 131072;
#pragma unroll
    for (int j = 0; j < 4; ++j) {
      float bv[4];
#pragma unroll
      for (int r = 0; r < 4; ++r) bv[r] = bias[n0 + wc * 64 + j * 16 + hi * 4 + r];
#pragma unroll
      for (int i = 0; i < 4; ++i) {
        // acc[i][j][r] = V[d = j*16+hi*4+r][t = tloc+i*16+ln]
        u16* p = ob + (((tloc >> 4) + i) * 64 + j * 16 + hi * 4) * 16 + ln;
#pragma unroll
        for (int r = 0; r < 4; ++r)
          p[r * 16] = f2b(acc[i][j][r] + bv[r]);
      }
    }
  } else {
    u16* ob = (which == 0 ? qw : kw) + bh * 131072;
    const float qs = (which == 0) ? 0.1803368801111244f : 1.0f;
    const int t5 = tloc >> 5;
#pragma unroll
    for (int j = 0; j < 4; ++j) {
      const float bv = bias[n0 + wc * 64 + j * 16 + ln];
#pragma unroll
      for (int i = 0; i < 4; ++i) {
        // t = tloc+i*16+hi*4+r, d = j*16+ln
        u16* p = ob + ((t5 + (i >> 1)) * 4 + j) * 512 + ((i & 1) * 16 + hi * 4) * 16 + ln;
#pragma unroll
        for (int r = 0; r < 4; ++r)
          p[r * 16] = f2b((acc[i][j][r] + bv) * qs);
      }
    }
  }
}

// ---------------- Flash attention v9d (superchunk x parity, V pipelined) ----------------
__global__ __launch_bounds__(128) void attn(
    const u16* __restrict__ qw, const u16* __restrict__ kw,
    const u16* __restrict__ vw, float* __restrict__ y) {
  // merge buffers per chunk: [parity][r][lane] (stride-1: conflict-free)
  __shared__ float accXA[2][16][64];
  __shared__ float lXA[2][16][64];
  __shared__ float accXB[2][16][64];
  __shared__ float lXB[2][16][64];

  const int lane = threadIdx.x & 63;
  const int p    = threadIdx.x >> 6;   // wave index == kv parity
  const int l31 = lane & 31;
  const int hi  = lane >> 5;
  const int laneoff = l31 * 16 + hi * 8;   // element offset inside a 512-elem frag slab

  // bid = xcd + 8*(pr + 16*bhg): all 16 blocks of one bh on one XCD.
  const int bid = blockIdx.x;
  const int xcd = bid & 7;
  const int rest = bid >> 3;               // 0..127
  const int pr  = rest & 15;               // superchunk pair 0..15
  const int bh  = xcd + 8 * (rest >> 4);   // 0..63
  const int bb  = bh >> 4, h = bh & 15;

  const u16* qb = qw + (size_t)bh * 131072;
  const u16* kb = kw + (size_t)bh * 131072;
  const u16* vb = vw + (size_t)bh * 131072;
  float* yb = y + (size_t)bb * 2048 * 1024 + (size_t)h * 64;

  bf16x8 onesf;
#pragma unroll
  for (int j = 0; j < 8; ++j) onesf[j] = (short)0x3F80;  // bf16 1.0

#pragma unroll 1
  for (int phase = 0; phase < 2; ++phase) {
    const int s  = phase ? (15 - pr) + 16 : pr;   // superchunks {pr, 31-pr}
    const int q0 = s * 64;
    const int cA = 2 * s, cB = 2 * s + 1;    // 32-row chunks
    const int jtE = cB;                      // kv tiles 0..2s+1

    // Q (B-operand) frags for both chunks
    bf16x8 qfA[4], qfB[4];
#pragma unroll
    for (int sb = 0; sb < 4; ++sb) {
      qfA[sb] = *(const bf16x8*)&qb[(cA * 4 + sb) * 512 + laneoff];
      qfB[sb] = *(const bf16x8*)&qb[(cB * 4 + sb) * 512 + laneoff];
    }

    f32x16 accA0, accA1, acclA, accB0, accB1, acclB;
#pragma unroll
    for (int r = 0; r < 16; ++r) {
      accA0[r] = 0.f; accA1[r] = 0.f; acclA[r] = 0.f;
      accB0[r] = 0.f; accB1[r] = 0.f; acclB[r] = 0.f;
    }

    // strength-reduced running pointers (tile jt: K at jt*2048, V at jt*2048;
    // jt advances by 2 -> both advance +4096 elems/iter)
    const u16* kpp = kb + laneoff + p * 2048;          // K tile jt=p
    const u16* vpp = vb + laneoff + p * 2048;          // V tile jt=p

    bf16x8 kf[4];
#pragma unroll
    for (int sb = 0; sb < 4; ++sb)
      kf[sb] = *(const bf16x8*)(kpp + sb * 512);

    // V prologue: vf = V(jt=p); in-loop reload vf = V(jt+2) after last use
    bf16x8 vf[4];
    vf[0] = *(const bf16x8*)(vpp);
    vf[1] = *(const bf16x8*)(vpp + 512);
    vf[2] = *(const bf16x8*)(vpp + 1024);
    vf[3] = *(const bf16x8*)(vpp + 1536);

#pragma unroll 1
    for (int jt = p; jt <= jtE; jt += 2) {
      // S^T = K_tile . Q^T for both chunks
      f32x16 stA, stB;
#pragma unroll
      for (int r = 0; r < 16; ++r) { stA[r] = 0.f; stB[r] = 0.f; }
#pragma unroll
      for (int sb = 0; sb < 4; ++sb) {
        stA = __builtin_amdgcn_mfma_f32_32x32x16_bf16(kf[sb], qfA[sb], stA, 0, 0, 0);
        stB = __builtin_amdgcn_mfma_f32_32x32x16_bf16(kf[sb], qfB[sb], stB, 0, 0, 0);
      }
      // K(jt) dead: reload jt+2 (exp2+PV covers latency)
      if (jt + 2 <= jtE) {
        const u16* kn = kpp + 4096;
#pragma unroll
        for (int sb = 0; sb < 4; ++sb)
          kf[sb] = *(const bf16x8*)(kn + sb * 512);
      }
      kpp += 4096;

      // masks (wave-uniform conditions; diagonals fall on fixed parities)
      if (jt == cA) {          // p=0: cA diagonal
#pragma unroll
        for (int r = 0; r < 16; ++r) {
          const int crow = (r & 3) + 8 * (r >> 2) + 4 * hi;
          if (crow > l31) stA[r] = -1e30f;
        }
      }
      if (jt == cB) {          // p=1: cA fully masked (P=0), cB diagonal
#pragma unroll
        for (int r = 0; r < 16; ++r) {
          const int crow = (r & 3) + 8 * (r >> 2) + 4 * hi;
          stA[r] = -1e30f;
          if (crow > l31) stB[r] = -1e30f;
        }
      }

      bf16x8 pa0, pa1;
      packP(stA, pa0, pa1);
      accA0 = __builtin_amdgcn_mfma_f32_32x32x16_bf16(pa0, vf[0], accA0, 0, 0, 0);
      accA1 = __builtin_amdgcn_mfma_f32_32x32x16_bf16(pa0, vf[1], accA1, 0, 0, 0);
      acclA = __builtin_amdgcn_mfma_f32_32x32x16_bf16(pa0, onesf, acclA, 0, 0, 0);
      accA0 = __builtin_amdgcn_mfma_f32_32x32x16_bf16(pa1, vf[2], accA0, 0, 0, 0);
      accA1 = __builtin_amdgcn_mfma_f32_32x32x16_bf16(pa1, vf[3], accA1, 0, 0, 0);
      acclA = __builtin_amdgcn_mfma_f32_32x32x16_bf16(pa1, onesf, acclA, 0, 0, 0);

      packP(stB, pa0, pa1);
      accB0 = __builtin_amdgcn_mfma_f32_32x32x16_bf16(pa0, vf[0], accB0, 0, 0, 0);
      accB1 = __builtin_amdgcn_mfma_f32_32x32x16_bf16(pa0, vf[1], accB1, 0, 0, 0);
      acclB = __builtin_amdgcn_mfma_f32_32x32x16_bf16(pa0, onesf, acclB, 0, 0, 0);
      accB0 = __builtin_amdgcn_mfma_f32_32x32x16_bf16(pa1, vf[2], accB0, 0, 0, 0);
      accB1 = __builtin_amdgcn_mfma_f32_32x32x16_bf16(pa1, vf[3], accB1, 0, 0, 0);
      acclB = __builtin_amdgcn_mfma_f32_32x32x16_bf16(pa1, onesf, acclB, 0, 0, 0);

      // V(jt) dead: reload vf = V(jt+2) (consumed next iter; ~1.7-step cover)
      if (jt + 2 <= jtE) {
        const u16* vn = vpp + 4096;
        vf[0] = *(const bf16x8*)(vn);
        vf[1] = *(const bf16x8*)(vn + 512);
        vf[2] = *(const bf16x8*)(vn + 1024);
        vf[3] = *(const bf16x8*)(vn + 1536);
      }
      vpp += 4096;
    }

    // ---- pair merge via LDS (linear: no max, no exp2) ----
    __syncthreads();   // protect previous phase's LDS reads
    if (p == 0) {
#pragma unroll
      for (int r = 0; r < 16; ++r) {
        accXA[0][r][lane] = accA1[r]; lXA[0][r][lane] = acclA[r];
        accXB[0][r][lane] = accB1[r]; lXB[0][r][lane] = acclB[r];
      }
    } else {
#pragma unroll
      for (int r = 0; r < 16; ++r) {
        accXA[1][r][lane] = accA0[r]; lXA[1][r][lane] = acclA[r];
        accXB[1][r][lane] = accB0[r]; lXB[1][r][lane] = acclB[r];
      }
    }
    __syncthreads();   // exports visible

    // p==0 merges d 0..31; p==1 merges d 32..63 (round-10 pattern, x2 chunks)
#pragma unroll
    for (int r = 0; r < 16; ++r) {
      const int crow = (r & 3) + 8 * (r >> 2) + 4 * hi;
      const float ownA = (p == 0) ? accA0[r] : accA1[r];
      const float othA = accXA[p ^ 1][r][lane];
      const float invA = 1.0f / (acclA[r] + lXA[p ^ 1][r][lane]);
      yb[(size_t)(q0 + crow) * 1024 + p * 32 + l31] = (ownA + othA) * invA;

      const float ownB = (p == 0) ? accB0[r] : accB1[r];
      const float othB = accXB[p ^ 1][r][lane];
      const float invB = 1.0f / (acclB[r] + lXB[p ^ 1][r][lane]);
      yb[(size_t)(q0 + 32 + crow) * 1024 + p * 32 + l31] = (ownB + othB) * invB;
    }
  }
}

extern "C" void kernel_launch(void* const* d_in, const int* in_sizes, int n_in,
                              void* d_out, int out_size, void* d_ws, size_t ws_size,
                              hipStream_t stream) {
  const float* x    = (const float*)d_in[0];   // [4,2048,1024]
  const float* W    = (const float*)d_in[1];   // [3072,1024]
  const float* bias = (const float*)d_in[2];   // [3072]
  float* y = (float*)d_out;

  char* ws = (char*)d_ws;
  u16* xb = (u16*)(ws);
  u16* Wb = (u16*)(ws + 16777216);
  u16* qw = (u16*)(ws + 23068672);
  u16* kw = (u16*)(ws + 39845888);
  u16* vw = (u16*)(ws + 56623104);

  cvt2<<<3072, 256, 0, stream>>>(x, xb, W, Wb);
  qkv_gemm<<<dim3(24, 64), 256, 0, stream>>>(xb, Wb, bias, qw, kw, vw);
  attn<<<1024, 128, 0, stream>>>(qw, kw, vw, y);
}